// Round 2
// baseline (417.255 us; speedup 1.0000x reference)
//
#include <hip/hip_runtime.h>
#include <hip/hip_cooperative_groups.h>

namespace cg = cooperative_groups;

#define NAG 256
#define HID 128
#define ACT 5
#define NH 4
#define DD 144      // concat dim
#define EE 576      // embed dim
#define HDIM 144    // per-head dim
#define CMAX 20     // fast-path neighbor cap
#define COOP_GRID_MAX 768

// ---------------------------------------------------------------------------
// Wave-split-K product tile: out[rowbase..+8, colbase..+64] =
//   A[rowbase..+8, 0..576) @ W[576 x N], A row-major stride 576.
// 4 waves split K (Kc=144); G=24 register double-buffer (fits 128-VGPR cap);
// LDS reduce. sm must hold >= 4640 floats (As 8x580, then red 2048 aliased).
// ---------------------------------------------------------------------------
__device__ __forceinline__ void prod_tile(
    const float* __restrict__ A, const float* __restrict__ W,
    float* __restrict__ out, int rowbase, int colbase, int N,
    int tid, float* __restrict__ sm)
{
    const int LDA = 580;
    float* As = sm;
    for (int idx = tid; idx < 8 * 144; idx += 256) {
        int r = idx / 144, c = idx % 144;
        *((float4*)&As[r * LDA + c * 4]) =
            *(const float4*)(A + (size_t)(rowbase + r) * 576 + c * 4);
    }
    __syncthreads();
    const int wave = tid >> 6, lane = tid & 63;
    const int colg = colbase + lane;
    const int colc = (colg < N) ? colg : (N - 1);
    const float* Wp = W + (size_t)(wave * 144) * N + colc;
    float acc[8] = {};
    float wv[24], wn[24];
    #pragma unroll
    for (int j = 0; j < 24; ++j) wv[j] = Wp[(size_t)j * N];
    for (int gi = 0; gi < 6; ++gi) {
        if (gi + 1 < 6) {
            const float* Wn = Wp + (size_t)(gi + 1) * 24 * N;
            #pragma unroll
            for (int j = 0; j < 24; ++j) wn[j] = Wn[(size_t)j * N];
        }
        const int kbase = wave * 144 + gi * 24;
        #pragma unroll
        for (int j4 = 0; j4 < 6; ++j4) {
            #pragma unroll
            for (int r = 0; r < 8; ++r) {
                float4 a4 = *(const float4*)&As[r * LDA + kbase + j4 * 4];
                acc[r] += a4.x * wv[j4 * 4 + 0] + a4.y * wv[j4 * 4 + 1]
                        + a4.z * wv[j4 * 4 + 2] + a4.w * wv[j4 * 4 + 3];
            }
        }
        #pragma unroll
        for (int j = 0; j < 24; ++j) wv[j] = wn[j];
    }
    __syncthreads();
    float* red = sm;
    #pragma unroll
    for (int r = 0; r < 8; ++r) red[wave * 512 + r * 64 + lane] = acc[r];
    __syncthreads();
    #pragma unroll
    for (int qq = 0; qq < 2; ++qq) {
        int idx = tid + qq * 256;
        int r = idx >> 6, cl = idx & 63;
        int col = colbase + cl;
        if (col < N) {
            float s = red[idx] + red[512 + idx] + red[1024 + idx] + red[1536 + idx];
            out[(size_t)(rowbase + r) * N + col] = s;
        }
    }
}

// ===========================================================================
// Cooperative fused kernel: 3 grid-stride phases, 2 grid.sync()s.
//  P1 (764 tasks): Wzc=Wz@Wiz (486), Wc=Wo@W_O (216), enc C (32), biases (30)
//  P2 (864 tasks): q/k/v = C @ Wzc + bzc
//  P3 (256 tasks): per-agent attention + tail (ctx/h stay in LDS)
// LDS 7504 floats = 30016 B (<32 KiB). VGPR capped via launch_bounds(256,4).
// Grid is sized by the HOST from the occupancy API; any grid >= 1 is correct.
// ===========================================================================
__global__ __launch_bounds__(256, 4) void k_fused(
    const float* __restrict__ hidden, const float* __restrict__ action,
    const int* __restrict__ state,
    const float* __restrict__ W_enc, const float* __restrict__ b_enc,
    const float* __restrict__ Wq, const float* __restrict__ bq,
    const float* __restrict__ Wk, const float* __restrict__ bk,
    const float* __restrict__ Wv, const float* __restrict__ bv,
    const float* __restrict__ Wiq, const float* __restrict__ biq,
    const float* __restrict__ Wik, const float* __restrict__ bik,
    const float* __restrict__ Wiv, const float* __restrict__ biv,
    const float* __restrict__ Wo, const float* __restrict__ bo,
    const float* __restrict__ W_O,
    const float* __restrict__ W_val, const float* __restrict__ b_val,
    const float* __restrict__ W_adv, const float* __restrict__ b_adv,
    float* __restrict__ C,
    float* __restrict__ Wqc, float* __restrict__ Wkc, float* __restrict__ Wvc,
    float* __restrict__ Wc,
    float* __restrict__ bqc, float* __restrict__ bkc, float* __restrict__ bvc,
    float* __restrict__ bvec,
    float* __restrict__ q, float* __restrict__ kb, float* __restrict__ v,
    float* __restrict__ out)
{
    // LDS aliasing:
    //  P1 prod: [0,4640)  P1 enc: Hs[0,1056) We[1056,3104)  P1 bias: [0,832)
    //  P2: As 8x148 [0,1184) then red [0,2048)
    //  P3: lst(int)[0,256) cnt[256] w4[260,1284) qh[1284,4184) kh[4184,7084)
    //      Sl[7084,7504); after heads done: ctx[1284,1860) h[1860,2004)
    __shared__ float smf[7504];
    const int bid = blockIdx.x, tid = threadIdx.x;
    const int gsz = gridDim.x;
    cg::grid_group gg = cg::this_grid();

    // ================= Phase 1: weight products, enc, biases ==============
    for (int t = bid; t < 764; t += gsz) {
        if (t < 486) {                          // qkv weight products
            const int g = t / 18, mb = t % 18;  // g 0..26
            const int z = g / 9, bx = g % 9;
            const float* A = (z == 0) ? Wq  : (z == 1) ? Wk  : Wv;
            const float* W = (z == 0) ? Wiq : (z == 1) ? Wik : Wiv;
            float*     o   = (z == 0) ? Wqc : (z == 1) ? Wkc : Wvc;
            prod_tile(A, W, o, mb * 8, bx * 64, EE, tid, smf);
        } else if (t < 702) {                   // Wc = Wo @ W_O
            const int s = t - 486;
            const int mb = s / 3, bx = s % 3;   // mb 0..71
            prod_tile(Wo, W_O, Wc, mb * 8, bx * 64, DD, tid, smf);
        } else if (t < 734) {                   // enc: C rows
            const int mb = t - 702;
            float* Hs = smf;                    // 8 x 132
            float* We = smf + 1056;             // 2048
            {
                int r = tid >> 5, kq = tid & 31;
                *((float4*)&Hs[r * 132 + kq * 4]) =
                    *(const float4*)(hidden + (mb * 8 + r) * HID + kq * 4);
                float4 a4 = *(const float4*)(action + (mb * 8 + r) * HID + kq * 4);
                *((float4*)(C + (size_t)(mb * 8 + r) * DD + 16 + kq * 4)) = a4;
                *((float4*)&We[tid * 4])        = *(const float4*)(W_enc + tid * 4);
                *((float4*)&We[1024 + tid * 4]) = *(const float4*)(W_enc + 1024 + tid * 4);
            }
            __syncthreads();
            if (tid < 128) {
                int r = tid >> 4, o = tid & 15;
                float acc = 0.f;
                #pragma unroll 8
                for (int d = 0; d < HID; ++d) acc += Hs[r * 132 + d] * We[d * 16 + o];
                C[(size_t)(mb * 8 + r) * DD + o] = acc + b_enc[o];
            }
        } else {                                // bias vectors
            const int tt = t - 734;             // 0..29
            const float *bsel, *W, *badd;
            float* o;
            int N, bx;
            if (tt < 27) {
                int z = tt / 9; bx = tt % 9; N = EE;
                bsel = (z == 0) ? bq  : (z == 1) ? bk  : bv;
                W    = (z == 0) ? Wiq : (z == 1) ? Wik : Wiv;
                badd = (z == 0) ? biq : (z == 1) ? bik : biv;
                o    = (z == 0) ? bqc : (z == 1) ? bkc : bvc;
            } else {
                bx = tt - 27; N = DD;
                bsel = bo; W = W_O; badd = nullptr; o = bvec;
            }
            float* bs = smf;                    // 576
            float* red = smf + 576;             // 256
            for (int i2 = tid; i2 < 144; i2 += 256)
                *((float4*)&bs[i2 * 4]) = *(const float4*)(bsel + i2 * 4);
            __syncthreads();
            const int wave = tid >> 6, lane = tid & 63;
            const int colg = bx * 64 + lane;
            const int colc = (colg < N) ? colg : (N - 1);
            float acc = 0.f;
            for (int k = wave * 144; k < wave * 144 + 144; ++k)
                acc += bs[k] * W[(size_t)k * N + colc];
            red[wave * 64 + lane] = acc;
            __syncthreads();
            if (tid < 64 && bx * 64 + tid < N) {
                float s = red[tid] + red[64 + tid] + red[128 + tid] + red[192 + tid];
                o[bx * 64 + tid] = s + (badd ? badd[bx * 64 + tid] : 0.f);
            }
        }
        __syncthreads();                        // protect smf reuse
    }
    __threadfence();
    gg.sync();

    // ================= Phase 2: q/k/v = C @ Wzc + bzc =====================
    for (int t = bid; t < 864; t += gsz) {
        const int g = t / 32, mb = t % 32;      // g 0..26
        const int z = g / 9, bx = g % 9;
        const float* W  = (z == 0) ? Wqc : (z == 1) ? Wkc : Wvc;
        const float* bi = (z == 0) ? bqc : (z == 1) ? bkc : bvc;
        float*     outp = (z == 0) ? q   : (z == 1) ? kb  : v;
        for (int idx = tid; idx < 8 * 36; idx += 256) {
            int r = idx / 36, cc = idx % 36;
            *((float4*)&smf[r * 148 + cc * 4]) =
                *(const float4*)(C + (size_t)(mb * 8 + r) * DD + cc * 4);
        }
        __syncthreads();
        const int wave = tid >> 6, lane = tid & 63;
        const int colg = bx * 64 + lane;
        const float* Wp = W + (size_t)(wave * 36) * EE + colg;
        float acc[8] = {};
        float wv[36];
        #pragma unroll
        for (int j = 0; j < 36; ++j) wv[j] = Wp[(size_t)j * EE];
        const int kbase = wave * 36;
        #pragma unroll
        for (int j4 = 0; j4 < 9; ++j4) {
            #pragma unroll
            for (int r = 0; r < 8; ++r) {
                float4 a4 = *(const float4*)&smf[r * 148 + kbase + j4 * 4];
                acc[r] += a4.x * wv[j4 * 4 + 0] + a4.y * wv[j4 * 4 + 1]
                        + a4.z * wv[j4 * 4 + 2] + a4.w * wv[j4 * 4 + 3];
            }
        }
        __syncthreads();
        #pragma unroll
        for (int r = 0; r < 8; ++r) smf[wave * 512 + r * 64 + lane] = acc[r];
        __syncthreads();
        #pragma unroll
        for (int qi = 0; qi < 2; ++qi) {
            int idx = tid + qi * 256;
            int r = idx >> 6, cl = idx & 63;
            int col = bx * 64 + cl;
            float s = smf[idx] + smf[512 + idx] + smf[1024 + idx] + smf[1536 + idx];
            outp[(size_t)(mb * 8 + r) * EE + col] = s + bi[col];
        }
        __syncthreads();                        // protect smf reuse
    }
    __threadfence();
    gg.sync();

    // ================= Phase 3: fused attention + tail ====================
    for (int i = bid; i < NAG; i += gsz) {
        int*  lst  = (int*)smf;                 // 256
        int*  cnts = (int*)(smf + 256);         // 1
        float* w4f = smf + 260;                 // [NH][NAG]
        float (*qh)[HDIM + 1] = (float(*)[HDIM + 1])(smf + 1284);
        float (*kh)[HDIM + 1] = (float(*)[HDIM + 1])(smf + 4184);
        float (*Sl)[CMAX + 1] = (float(*)[CMAX + 1])(smf + 7084);
        float* ctxs = smf + 1284;               // aliases dead qh (576)
        float* hs   = smf + 1860;               // 144

        if (tid == 0) *cnts = 0;
        __syncthreads();
        {
            int xi = state[2 * i], yi = state[2 * i + 1];
            int xj = state[2 * tid], yj = state[2 * tid + 1];
            int dx = xi - xj; if (dx < 0) dx = -dx;
            int dy = yi - yj; if (dy < 0) dy = -dy;
            if (tid > i && dx <= 4 && dy <= 2) {
                int p = atomicAdd(cnts, 1);
                lst[p] = tid;
            }
        }
        __syncthreads();
        const int c = *cnts;                    // block-uniform
        if (c > 0 && c <= CMAX) {
            for (int h = 0; h < NH; ++h) {
                for (int idx = tid; idx < c * HDIM; idx += 256) {
                    int jj = idx / HDIM, d = idx % HDIM;
                    qh[jj][d] = q[lst[jj] * EE + h * HDIM + d];
                    kh[jj][d] = kb[lst[jj] * EE + h * HDIM + d];
                }
                __syncthreads();
                for (int pp = tid; pp < c * c; pp += 256) {
                    int jj = pp / c, kk = pp % c;
                    float acc = 0.f;
                    for (int d = 0; d < HDIM; ++d) acc += qh[jj][d] * kh[kk][d];
                    Sl[jj][kk] = acc * (1.0f / 12.0f);
                }
                __syncthreads();
                if (tid < c) {
                    float m = -1e30f;
                    for (int kk = 0; kk < c; ++kk) m = fmaxf(m, Sl[tid][kk]);
                    float zz = 0.f;
                    for (int kk = 0; kk < c; ++kk) zz += __expf(Sl[tid][kk] - m);
                    float inv = 1.f / fmaxf(zz, 1e-9f);
                    for (int kk = 0; kk < c; ++kk)
                        Sl[tid][kk] = __expf(Sl[tid][kk] - m) * inv;
                }
                __syncthreads();
                if (tid < c) {
                    float s = 0.f;
                    for (int jj = 0; jj < c; ++jj) s += Sl[jj][tid];
                    w4f[h * NAG + tid] = s;
                }
                __syncthreads();
            }
        } else if (c > CMAX) {
            for (int idx = tid; idx < NH * c; idx += 256)
                w4f[(idx / c) * NAG + (idx % c)] = 0.f;
            __syncthreads();
            for (int pnh = tid; pnh < NH * c; pnh += 256) {
                int h = pnh / c, jj = pnh % c;
                const float* qrow = q + lst[jj] * EE + h * HDIM;
                float m = -1e30f;
                for (int kk = 0; kk < c; ++kk) {
                    const float* krow = kb + lst[kk] * EE + h * HDIM;
                    float a = 0.f;
                    for (int d = 0; d < HDIM; ++d) a += qrow[d] * krow[d];
                    m = fmaxf(m, a * (1.0f / 12.0f));
                }
                float zz = 0.f;
                for (int kk = 0; kk < c; ++kk) {
                    const float* krow = kb + lst[kk] * EE + h * HDIM;
                    float a = 0.f;
                    for (int d = 0; d < HDIM; ++d) a += qrow[d] * krow[d];
                    zz += __expf(a * (1.0f / 12.0f) - m);
                }
                float inv = 1.f / fmaxf(zz, 1e-9f);
                for (int kk = 0; kk < c; ++kk) {
                    const float* krow = kb + lst[kk] * EE + h * HDIM;
                    float a = 0.f;
                    for (int d = 0; d < HDIM; ++d) a += qrow[d] * krow[d];
                    atomicAdd(&w4f[h * NAG + kk], __expf(a * (1.0f / 12.0f) - m) * inv);
                }
            }
            __syncthreads();
        }
        if (c > 0) {
            for (int e = tid; e < EE; e += 256) {
                int h = e / HDIM;
                float a0 = 0.f, a1 = 0.f;
                int t2 = 0;
                for (; t2 + 1 < c; t2 += 2) {
                    a0 += w4f[h * NAG + t2] * v[lst[t2] * EE + e];
                    a1 += w4f[h * NAG + t2 + 1] * v[lst[t2 + 1] * EE + e];
                }
                if (t2 < c) a0 += w4f[h * NAG + t2] * v[lst[t2] * EE + e];
                ctxs[e] = a0 + a1;
            }
        }
        __syncthreads();
        // tail: h = ctx @ Wc + c*bvec (ctx and h stay in LDS)
        if (tid < DD) {
            float acc = 0.f;
            if (c > 0) {
                const float* Wp = Wc + tid;
                #pragma unroll 8
                for (int k2 = 0; k2 < EE; ++k2) acc += ctxs[k2] * Wp[(size_t)k2 * DD];
            }
            hs[tid] = acc + (float)c * bvec[tid];
        }
        __syncthreads();
        // dueling head on wave 0
        if (tid < 64) {
            const int lane = tid;
            float h0 = hs[lane], h1 = hs[lane + 64];
            float h2 = (lane < 16) ? hs[lane + 128] : 0.f;
            float red6[6];
            for (int o = 0; o < 6; ++o) {
                float p2;
                if (o < 5) {
                    p2 = h0 * W_adv[lane * ACT + o] + h1 * W_adv[(lane + 64) * ACT + o];
                    if (lane < 16) p2 += h2 * W_adv[(lane + 128) * ACT + o];
                } else {
                    p2 = h0 * W_val[lane] + h1 * W_val[lane + 64];
                    if (lane < 16) p2 += h2 * W_val[lane + 128];
                }
                for (int off = 32; off; off >>= 1) p2 += __shfl_xor(p2, off);
                red6[o] = p2;
            }
            if (lane == 0) {
                float a[ACT], mean = 0.f;
                for (int o = 0; o < ACT; ++o) { a[o] = red6[o] + b_adv[o]; mean += a[o]; }
                mean *= (1.0f / ACT);
                float V = red6[5] + b_val[0];
                for (int o = 0; o < ACT; ++o) out[i * ACT + o] = V + a[o] - mean;
            }
        }
        __syncthreads();                        // protect smf reuse
    }
}

// ===========================================================================
// FALLBACK PATH — verbatim round-0 kernels (proven, 193 us). Used only if the
// cooperative launch is rejected by the runtime.
// ===========================================================================
__global__ __launch_bounds__(256) void k_pre(
    const float* __restrict__ hidden, const float* __restrict__ action,
    const float* __restrict__ W_enc, const float* __restrict__ b_enc,
    const float* __restrict__ Wq, const float* __restrict__ Wk, const float* __restrict__ Wv,
    const float* __restrict__ bq, const float* __restrict__ bk, const float* __restrict__ bv,
    const float* __restrict__ Wiq, const float* __restrict__ Wik, const float* __restrict__ Wiv,
    const float* __restrict__ biq, const float* __restrict__ bik, const float* __restrict__ biv,
    const float* __restrict__ Wo, const float* __restrict__ bo, const float* __restrict__ W_O,
    float* __restrict__ C,
    float* __restrict__ Wqc, float* __restrict__ Wkc, float* __restrict__ Wvc,
    float* __restrict__ Wc,
    float* __restrict__ bqc, float* __restrict__ bkc, float* __restrict__ bvc,
    float* __restrict__ bvec)
{
    __shared__ float sm[4640];
    const int p = blockIdx.x, tid = threadIdx.x;
    if (p < 576) {
        const int xcd = p & 7, r = p >> 3;
        const int gslot = r / 18, mb = r % 18;
        const int g = xcd + 8 * gslot;
        if (g >= 27) return;
        const int bx = g % 9, z = g / 9;
        const float* A = (z == 0) ? Wq  : (z == 1) ? Wk  : Wv;
        const float* W = (z == 0) ? Wiq : (z == 1) ? Wik : Wiv;
        float*     out = (z == 0) ? Wqc : (z == 1) ? Wkc : Wvc;
        prod_tile(A, W, out, mb * 8, bx * 64, EE, tid, sm);
    } else if (p < 1152) {
        const int pp = p - 576;
        const int xcd = pp & 7, mb = pp >> 3;
        if (xcd >= 3) return;
        prod_tile(Wo, W_O, Wc, mb * 8, xcd * 64, DD, tid, sm);
    } else if (p < 1184) {
        const int mb = p - 1152;
        float* Hs = sm;
        float* We = sm + 1056;
        {
            int r = tid >> 5, kq = tid & 31;
            *((float4*)&Hs[r * 132 + kq * 4]) =
                *(const float4*)(hidden + (mb * 8 + r) * HID + kq * 4);
            float4 a4 = *(const float4*)(action + (mb * 8 + r) * HID + kq * 4);
            *((float4*)(C + (size_t)(mb * 8 + r) * DD + 16 + kq * 4)) = a4;
            *((float4*)&We[tid * 4])        = *(const float4*)(W_enc + tid * 4);
            *((float4*)&We[1024 + tid * 4]) = *(const float4*)(W_enc + 1024 + tid * 4);
        }
        __syncthreads();
        if (tid < 128) {
            int r = tid >> 4, o = tid & 15;
            float acc = 0.f;
            #pragma unroll 8
            for (int d = 0; d < HID; ++d) acc += Hs[r * 132 + d] * We[d * 16 + o];
            C[(size_t)(mb * 8 + r) * DD + o] = acc + b_enc[o];
        }
    } else {
        const int t = p - 1184;
        const float *bsel, *W, *badd;
        float* out;
        int N, bx;
        if (t < 27) {
            int z = t / 9; bx = t % 9; N = EE;
            bsel = (z == 0) ? bq  : (z == 1) ? bk  : bv;
            W    = (z == 0) ? Wiq : (z == 1) ? Wik : Wiv;
            badd = (z == 0) ? biq : (z == 1) ? bik : biv;
            out  = (z == 0) ? bqc : (z == 1) ? bkc : bvc;
        } else {
            bx = t - 27; N = DD;
            bsel = bo; W = W_O; badd = nullptr; out = bvec;
        }
        float* bs = sm;
        float* red = sm + 576;
        for (int i = tid; i < 144; i += 256)
            *((float4*)&bs[i * 4]) = *(const float4*)(bsel + i * 4);
        __syncthreads();
        const int wave = tid >> 6, lane = tid & 63;
        const int colg = bx * 64 + lane;
        const int colc = (colg < N) ? colg : (N - 1);
        float acc = 0.f;
        for (int k = wave * 144; k < wave * 144 + 144; ++k)
            acc += bs[k] * W[(size_t)k * N + colc];
        red[wave * 64 + lane] = acc;
        __syncthreads();
        if (tid < 64 && bx * 64 + tid < N) {
            float s = red[tid] + red[64 + tid] + red[128 + tid] + red[192 + tid];
            out[bx * 64 + tid] = s + (badd ? badd[bx * 64 + tid] : 0.f);
        }
    }
}

__global__ __launch_bounds__(256) void k_qkv(
    const float* __restrict__ C,
    const float* __restrict__ Wqc, const float* __restrict__ Wkc, const float* __restrict__ Wvc,
    const float* __restrict__ bqc, const float* __restrict__ bkc, const float* __restrict__ bvc,
    float* __restrict__ q, float* __restrict__ kb, float* __restrict__ v)
{
    const int p = blockIdx.x;
    const int xcd = p & 7, qq = p >> 3;
    const int mb = qq & 31, gslot = qq >> 5;
    const int g = xcd + 8 * gslot;
    if (g >= 27) return;
    const int bx = g % 9, z = g / 9;
    const float* W  = (z == 0) ? Wqc : (z == 1) ? Wkc : Wvc;
    const float* bi = (z == 0) ? bqc : (z == 1) ? bkc : bvc;
    float*      out = (z == 0) ? q   : (z == 1) ? kb  : v;
    const int tid = threadIdx.x;

    __shared__ union { float As[8 * 148]; float red[2048]; } u;
    for (int idx = tid; idx < 8 * 36; idx += 256) {
        int r = idx / 36, c = idx % 36;
        *((float4*)&u.As[r * 148 + c * 4]) =
            *(const float4*)(C + (size_t)(mb * 8 + r) * DD + c * 4);
    }
    __syncthreads();
    const int wave = tid >> 6, lane = tid & 63;
    const int colg = bx * 64 + lane;
    const float* Wp = W + (size_t)(wave * 36) * EE + colg;
    float acc[8] = {};
    float wv[36];
    #pragma unroll
    for (int j = 0; j < 36; ++j) wv[j] = Wp[(size_t)j * EE];
    const int kbase = wave * 36;
    #pragma unroll
    for (int j4 = 0; j4 < 9; ++j4) {
        #pragma unroll
        for (int r = 0; r < 8; ++r) {
            float4 a4 = *(const float4*)&u.As[r * 148 + kbase + j4 * 4];
            acc[r] += a4.x * wv[j4 * 4 + 0] + a4.y * wv[j4 * 4 + 1]
                    + a4.z * wv[j4 * 4 + 2] + a4.w * wv[j4 * 4 + 3];
        }
    }
    __syncthreads();
    #pragma unroll
    for (int r = 0; r < 8; ++r) u.red[wave * 512 + r * 64 + lane] = acc[r];
    __syncthreads();
    #pragma unroll
    for (int qi = 0; qi < 2; ++qi) {
        int idx = tid + qi * 256;
        int r = idx >> 6, cl = idx & 63;
        int col = bx * 64 + cl;
        float s = u.red[idx] + u.red[512 + idx]
                + u.red[1024 + idx] + u.red[1536 + idx];
        out[(size_t)(mb * 8 + r) * EE + col] = s + bi[col];
    }
}

__global__ __launch_bounds__(256) void k_attn(
    const int* __restrict__ state, const float* __restrict__ q,
    const float* __restrict__ kmat, const float* __restrict__ v,
    float* __restrict__ ctxsum, float* __restrict__ cnt)
{
    __shared__ int lst[NAG];
    __shared__ int cnt_s;
    __shared__ float w4[NH][NAG];
    __shared__ float qh[CMAX][HDIM + 1];
    __shared__ float kh[CMAX][HDIM + 1];
    __shared__ float Sl[CMAX][CMAX + 1];
    const int i = blockIdx.x, tid = threadIdx.x;
    if (tid == 0) cnt_s = 0;
    __syncthreads();
    {
        int xi = state[2 * i], yi = state[2 * i + 1];
        int xj = state[2 * tid], yj = state[2 * tid + 1];
        int dx = xi - xj; if (dx < 0) dx = -dx;
        int dy = yi - yj; if (dy < 0) dy = -dy;
        if (tid > i && dx <= 4 && dy <= 2) {
            int p = atomicAdd(&cnt_s, 1);
            lst[p] = tid;
        }
    }
    __syncthreads();
    const int c = cnt_s;
    if (tid == 0) cnt[i] = (float)c;
    if (c == 0) {
        for (int e = tid; e < EE; e += 256) ctxsum[i * EE + e] = 0.f;
        return;
    }
    if (c <= CMAX) {
        for (int h = 0; h < NH; ++h) {
            for (int idx = tid; idx < c * HDIM; idx += 256) {
                int jj = idx / HDIM, d = idx % HDIM;
                qh[jj][d] = q[lst[jj] * EE + h * HDIM + d];
                kh[jj][d] = kmat[lst[jj] * EE + h * HDIM + d];
            }
            __syncthreads();
            for (int pp = tid; pp < c * c; pp += 256) {
                int jj = pp / c, kk = pp % c;
                float acc = 0.f;
                for (int d = 0; d < HDIM; ++d) acc += qh[jj][d] * kh[kk][d];
                Sl[jj][kk] = acc * (1.0f / 12.0f);
            }
            __syncthreads();
            if (tid < c) {
                float m = -1e30f;
                for (int kk = 0; kk < c; ++kk) m = fmaxf(m, Sl[tid][kk]);
                float zz = 0.f;
                for (int kk = 0; kk < c; ++kk) zz += __expf(Sl[tid][kk] - m);
                float inv = 1.f / fmaxf(zz, 1e-9f);
                for (int kk = 0; kk < c; ++kk)
                    Sl[tid][kk] = __expf(Sl[tid][kk] - m) * inv;
            }
            __syncthreads();
            if (tid < c) {
                float s = 0.f;
                for (int jj = 0; jj < c; ++jj) s += Sl[jj][tid];
                w4[h][tid] = s;
            }
            __syncthreads();
        }
    } else {
        for (int idx = tid; idx < NH * c; idx += 256) w4[idx / c][idx % c] = 0.f;
        __syncthreads();
        for (int pnh = tid; pnh < NH * c; pnh += 256) {
            int h = pnh / c, jj = pnh % c;
            const float* qrow = q + lst[jj] * EE + h * HDIM;
            float m = -1e30f;
            for (int kk = 0; kk < c; ++kk) {
                const float* krow = kmat + lst[kk] * EE + h * HDIM;
                float a = 0.f;
                for (int d = 0; d < HDIM; ++d) a += qrow[d] * krow[d];
                m = fmaxf(m, a * (1.0f / 12.0f));
            }
            float zz = 0.f;
            for (int kk = 0; kk < c; ++kk) {
                const float* krow = kmat + lst[kk] * EE + h * HDIM;
                float a = 0.f;
                for (int d = 0; d < HDIM; ++d) a += qrow[d] * krow[d];
                zz += __expf(a * (1.0f / 12.0f) - m);
            }
            float inv = 1.f / fmaxf(zz, 1e-9f);
            for (int kk = 0; kk < c; ++kk) {
                const float* krow = kmat + lst[kk] * EE + h * HDIM;
                float a = 0.f;
                for (int d = 0; d < HDIM; ++d) a += qrow[d] * krow[d];
                atomicAdd(&w4[h][kk], __expf(a * (1.0f / 12.0f) - m) * inv);
            }
        }
        __syncthreads();
    }
    for (int e = tid; e < EE; e += 256) {
        int h = e / HDIM;
        float a0 = 0.f, a1 = 0.f;
        int t = 0;
        for (; t + 1 < c; t += 2) {
            a0 += w4[h][t] * v[lst[t] * EE + e];
            a1 += w4[h][t + 1] * v[lst[t + 1] * EE + e];
        }
        if (t < c) a0 += w4[h][t] * v[lst[t] * EE + e];
        ctxsum[i * EE + e] = a0 + a1;
    }
}

__global__ __launch_bounds__(256) void k_tail(
    const float* __restrict__ ctx, const float* __restrict__ Wc,
    const float* __restrict__ cnt, const float* __restrict__ bvec,
    const float* __restrict__ W_val, const float* __restrict__ b_val,
    const float* __restrict__ W_adv, const float* __restrict__ b_adv,
    float* __restrict__ out)
{
    __shared__ float As[4][EE];
    __shared__ float hb[4][DD];
    const int b = blockIdx.x, tid = threadIdx.x;
    const int a0 = b * 4;
    for (int idx = tid; idx < 4 * (EE / 4); idx += 256) {
        int r = idx / (EE / 4), c4 = idx % (EE / 4);
        *((float4*)&As[r][c4 * 4]) =
            *(const float4*)(ctx + (size_t)(a0 + r) * EE + c4 * 4);
    }
    __syncthreads();
    if (tid < DD) {
        const int col = tid;
        const float* Wp = Wc + col;
        float ac0 = 0.f, ac1 = 0.f, ac2 = 0.f, ac3 = 0.f;
        float wv[32], wn[32];
        #pragma unroll
        for (int j = 0; j < 32; ++j) wv[j] = Wp[(size_t)j * DD];
        for (int gI = 0; gI < 18; ++gI) {
            if (gI + 1 < 18) {
                const float* Wn = Wp + (size_t)(gI + 1) * 32 * DD;
                #pragma unroll
                for (int j = 0; j < 32; ++j) wn[j] = Wn[(size_t)j * DD];
            }
            const int kbase = gI * 32;
            #pragma unroll
            for (int j = 0; j < 32; ++j) {
                float w = wv[j];
                ac0 += As[0][kbase + j] * w; ac1 += As[1][kbase + j] * w;
                ac2 += As[2][kbase + j] * w; ac3 += As[3][kbase + j] * w;
            }
            #pragma unroll
            for (int j = 0; j < 32; ++j) wv[j] = wn[j];
        }
        float bvc = bvec[col];
        hb[0][col] = ac0 + cnt[a0 + 0] * bvc;
        hb[1][col] = ac1 + cnt[a0 + 1] * bvc;
        hb[2][col] = ac2 + cnt[a0 + 2] * bvc;
        hb[3][col] = ac3 + cnt[a0 + 3] * bvc;
    }
    __syncthreads();
    const int wave = tid >> 6, lane = tid & 63;
    float h0 = hb[wave][lane], h1 = hb[wave][lane + 64];
    float h2 = (lane < 16) ? hb[wave][lane + 128] : 0.f;
    float red[6];
    for (int o = 0; o < 6; ++o) {
        float p;
        if (o < 5) {
            p = h0 * W_adv[lane * ACT + o] + h1 * W_adv[(lane + 64) * ACT + o];
            if (lane < 16) p += h2 * W_adv[(lane + 128) * ACT + o];
        } else {
            p = h0 * W_val[lane] + h1 * W_val[lane + 64];
            if (lane < 16) p += h2 * W_val[lane + 128];
        }
        for (int off = 32; off; off >>= 1) p += __shfl_xor(p, off);
        red[o] = p;
    }
    if (lane == 0) {
        float a[ACT], mean = 0.f;
        for (int o = 0; o < ACT; ++o) { a[o] = red[o] + b_adv[o]; mean += a[o]; }
        mean *= (1.0f / ACT);
        float V = red[5] + b_val[0];
        for (int o = 0; o < ACT; ++o) out[(a0 + wave) * ACT + o] = V + a[o] - mean;
    }
}

// ---------------------------------------------------------------------------
extern "C" void kernel_launch(void* const* d_in, const int* in_sizes, int n_in,
                              void* d_out, int out_size, void* d_ws, size_t ws_size,
                              hipStream_t stream)
{
    float* ws = (float*)d_ws;
    float* C    = ws;                        // 256*144
    float* Wqc  = C    + NAG * DD;           // 144*576 each
    float* Wkc  = Wqc  + DD * EE;
    float* Wvc  = Wkc  + DD * EE;
    float* Wc   = Wvc  + DD * EE;            // 576*144
    float* bqc  = Wc   + EE * DD;            // 576 each
    float* bkc  = bqc  + EE;
    float* bvc  = bkc  + EE;
    float* bvec = bvc  + EE;                 // 144
    float* q    = bvec + DD;                 // 256*576 each
    float* kb   = q    + NAG * EE;
    float* v    = kb   + NAG * EE;
    float* ctx  = v    + NAG * EE;           // fallback only
    float* cnt  = ctx  + NAG * EE;           // fallback only

    const float* hidden = (const float*)d_in[0];
    const float* action = (const float*)d_in[1];
    const int*   state  = (const int*)d_in[2];
    const float* W_enc  = (const float*)d_in[3];
    const float* b_enc  = (const float*)d_in[4];
    const float* Wq     = (const float*)d_in[5];
    const float* bq     = (const float*)d_in[6];
    const float* Wk     = (const float*)d_in[7];
    const float* bk     = (const float*)d_in[8];
    const float* Wv     = (const float*)d_in[9];
    const float* bv     = (const float*)d_in[10];
    const float* Wiq    = (const float*)d_in[11];
    const float* biq    = (const float*)d_in[12];
    const float* Wik    = (const float*)d_in[13];
    const float* bik    = (const float*)d_in[14];
    const float* Wiv    = (const float*)d_in[15];
    const float* biv    = (const float*)d_in[16];
    const float* Wo     = (const float*)d_in[17];
    const float* bo     = (const float*)d_in[18];
    const float* W_O    = (const float*)d_in[19];
    const float* W_val  = (const float*)d_in[20];
    const float* b_val  = (const float*)d_in[21];
    const float* W_adv  = (const float*)d_in[22];
    const float* b_adv  = (const float*)d_in[23];
    float* outp = (float*)d_out;

    // Decide cooperative grid once: runtime-reported capacity, clamped.
    static int coop_grid = 0;                // 0 undecided, -1 disabled, >0 grid
    if (coop_grid == 0) {
        int perCU = 0;
        hipError_t e1 = hipOccupancyMaxActiveBlocksPerMultiprocessor(
            &perCU, k_fused, 256, 0);
        hipDeviceProp_t prop;
        int dev = 0;
        hipGetDevice(&dev);
        hipError_t e2 = hipGetDeviceProperties(&prop, dev);
        if (e1 == hipSuccess && e2 == hipSuccess && perCU > 0) {
            long cap = (long)perCU * (long)prop.multiProcessorCount;
            coop_grid = (int)((cap < COOP_GRID_MAX) ? cap : COOP_GRID_MAX);
        } else {
            coop_grid = -1;
        }
    }

    bool done = false;
    if (coop_grid > 0) {
        void* args[] = {
            (void*)&hidden, (void*)&action, (void*)&state,
            (void*)&W_enc, (void*)&b_enc,
            (void*)&Wq, (void*)&bq, (void*)&Wk, (void*)&bk, (void*)&Wv, (void*)&bv,
            (void*)&Wiq, (void*)&biq, (void*)&Wik, (void*)&bik, (void*)&Wiv, (void*)&biv,
            (void*)&Wo, (void*)&bo, (void*)&W_O,
            (void*)&W_val, (void*)&b_val, (void*)&W_adv, (void*)&b_adv,
            (void*)&C, (void*)&Wqc, (void*)&Wkc, (void*)&Wvc, (void*)&Wc,
            (void*)&bqc, (void*)&bkc, (void*)&bvc, (void*)&bvec,
            (void*)&q, (void*)&kb, (void*)&v, (void*)&outp
        };
        hipError_t le = hipLaunchCooperativeKernel(
            k_fused, dim3(coop_grid), dim3(256), args, 0, stream);
        if (le == hipSuccess) {
            done = true;
        } else {
            coop_grid = -1;                  // never retry coop
        }
    }

    if (!done) {
        // Proven 4-kernel fallback (round-0 path, 193 us)
        k_pre<<<1214, 256, 0, stream>>>(hidden, action, W_enc, b_enc,
            Wq, Wk, Wv, bq, bk, bv, Wiq, Wik, Wiv, biq, bik, biv,
            Wo, bo, W_O, C, Wqc, Wkc, Wvc, Wc, bqc, bkc, bvc, bvec);
        k_qkv<<<1024, 256, 0, stream>>>(C, Wqc, Wkc, Wvc, bqc, bkc, bvc, q, kb, v);
        k_attn<<<NAG, 256, 0, stream>>>(state, q, kb, v, ctx, cnt);
        k_tail<<<64, 256, 0, stream>>>(ctx, Wc, cnt, bvec,
            W_val, b_val, W_adv, b_adv, outp);
    }
}

// Round 3
// 193.733 us; speedup vs baseline: 2.1538x; 2.1538x over previous
//
#include <hip/hip_runtime.h>

#define NAG 256
#define HID 128
#define ACT 5
#define NH 4
#define DD 144      // concat dim
#define EE 576      // embed dim
#define HDIM 144    // per-head dim
#define CMAX 20     // fast-path neighbor cap

// ---------------------------------------------------------------------------
// Wave-split-K product tile, R=24 rows: out[rowbase..+24, colbase..+64] =
//   A[rowbase..+24, 0..576) @ W[576 x N], A row-major stride 576.
// 4 waves split K (144 each); G=24 register double-buffer; LDS reduce.
// sm must hold >= 13920 floats (As 24x580; red 6144 aliased after compute).
// W panel (147 KB) read ONCE per 24 output rows (was once per 8) -> 3x less
// panel traffic than the proven R=8 version, which dominated k_pre.
// ---------------------------------------------------------------------------
__device__ __forceinline__ void prod_tile24(
    const float* __restrict__ A, const float* __restrict__ W,
    float* __restrict__ out, int rowbase, int colbase, int N,
    int tid, float* __restrict__ sm)
{
    const int LDA = 580;
    float* As = sm;
    for (int idx = tid; idx < 24 * 144; idx += 256) {
        int r = idx / 144, c = idx % 144;
        *((float4*)&As[r * LDA + c * 4]) =
            *(const float4*)(A + (size_t)(rowbase + r) * 576 + c * 4);
    }
    __syncthreads();
    const int wave = tid >> 6, lane = tid & 63;
    const int colg = colbase + lane;
    const int colc = (colg < N) ? colg : (N - 1);
    const float* Wp = W + (size_t)(wave * 144) * N + colc;
    float acc[24] = {};
    float wv[24], wn[24];
    #pragma unroll
    for (int j = 0; j < 24; ++j) wv[j] = Wp[(size_t)j * N];
    for (int gi = 0; gi < 6; ++gi) {
        if (gi + 1 < 6) {
            const float* Wn = Wp + (size_t)(gi + 1) * 24 * N;
            #pragma unroll
            for (int j = 0; j < 24; ++j) wn[j] = Wn[(size_t)j * N];
        }
        const int kb = wave * 144 + gi * 24;
        #pragma unroll
        for (int j4 = 0; j4 < 6; ++j4) {
            #pragma unroll
            for (int r = 0; r < 24; ++r) {
                float4 a4 = *(const float4*)&As[r * LDA + kb + j4 * 4];
                acc[r] += a4.x * wv[j4 * 4 + 0] + a4.y * wv[j4 * 4 + 1]
                        + a4.z * wv[j4 * 4 + 2] + a4.w * wv[j4 * 4 + 3];
            }
        }
        #pragma unroll
        for (int j = 0; j < 24; ++j) wv[j] = wn[j];
    }
    __syncthreads();
    float* red = sm;                         // 4 x 24 x 64 = 6144, aliases As
    #pragma unroll
    for (int r = 0; r < 24; ++r) red[wave * 1536 + r * 64 + lane] = acc[r];
    __syncthreads();
    #pragma unroll
    for (int qq = 0; qq < 6; ++qq) {
        int idx = tid + qq * 256;
        int r = idx >> 6, cl = idx & 63;
        int col = colbase + cl;
        if (col < N) {
            float s = red[idx] + red[1536 + idx] + red[3072 + idx] + red[4608 + idx];
            out[(size_t)(rowbase + r) * N + col] = s;
        }
    }
}

// ---------------------------------------------------------------------------
// k_pre (296 blocks): weight products (R=24 tiles), enc C, bias vectors.
//  [0,162)    qkv products: Wzc = Wz @ Wiz   (27 panels x 6 row-tiles)
//  [162,234)  Wc = Wo @ W_O                  (24 row-tiles x 3 col-blocks)
//  [234,266)  C  = concat(enc(hidden), action)  (32 blocks)
//  [266,296)  bzc = bz@Wiz + biz (27) ; bvec = bo@W_O (3)
// ---------------------------------------------------------------------------
__global__ __launch_bounds__(256) void k_pre(
    const float* __restrict__ hidden, const float* __restrict__ action,
    const float* __restrict__ W_enc, const float* __restrict__ b_enc,
    const float* __restrict__ Wq, const float* __restrict__ Wk, const float* __restrict__ Wv,
    const float* __restrict__ bq, const float* __restrict__ bk, const float* __restrict__ bv,
    const float* __restrict__ Wiq, const float* __restrict__ Wik, const float* __restrict__ Wiv,
    const float* __restrict__ biq, const float* __restrict__ bik, const float* __restrict__ biv,
    const float* __restrict__ Wo, const float* __restrict__ bo, const float* __restrict__ W_O,
    float* __restrict__ C,
    float* __restrict__ Wqc, float* __restrict__ Wkc, float* __restrict__ Wvc,
    float* __restrict__ Wc,
    float* __restrict__ bqc, float* __restrict__ bkc, float* __restrict__ bvc,
    float* __restrict__ bvec)
{
    __shared__ float sm[13920];              // 55.7 KB (< 64 KB static limit)
    const int p = blockIdx.x, tid = threadIdx.x;
    if (p < 162) {                           // qkv weight products
        const int g = p / 6, mt = p % 6;     // g 0..26, mt 0..5 (24-row tiles)
        const int z = g / 9, bx = g % 9;
        const float* A = (z == 0) ? Wq  : (z == 1) ? Wk  : Wv;
        const float* W = (z == 0) ? Wiq : (z == 1) ? Wik : Wiv;
        float*     out = (z == 0) ? Wqc : (z == 1) ? Wkc : Wvc;
        prod_tile24(A, W, out, mt * 24, bx * 64, EE, tid, sm);
    } else if (p < 234) {                    // Wc = Wo @ W_O
        const int t = p - 162;
        const int mt = t / 3, bx = t % 3;    // mt 0..23 (576 rows), bx 0..2
        prod_tile24(Wo, W_O, Wc, mt * 24, bx * 64, DD, tid, sm);
    } else if (p < 266) {                    // enc C
        const int mb = p - 234;
        float* Hs = sm;                      // 8 x 132
        float* We = sm + 1056;               // 2048
        {
            int r = tid >> 5, kq = tid & 31;
            *((float4*)&Hs[r * 132 + kq * 4]) =
                *(const float4*)(hidden + (mb * 8 + r) * HID + kq * 4);
            float4 a4 = *(const float4*)(action + (mb * 8 + r) * HID + kq * 4);
            *((float4*)(C + (size_t)(mb * 8 + r) * DD + 16 + kq * 4)) = a4;
            *((float4*)&We[tid * 4])        = *(const float4*)(W_enc + tid * 4);
            *((float4*)&We[1024 + tid * 4]) = *(const float4*)(W_enc + 1024 + tid * 4);
        }
        __syncthreads();
        if (tid < 128) {
            int r = tid >> 4, o = tid & 15;
            float acc = 0.f;
            #pragma unroll 8
            for (int d = 0; d < HID; ++d) acc += Hs[r * 132 + d] * We[d * 16 + o];
            C[(size_t)(mb * 8 + r) * DD + o] = acc + b_enc[o];
        }
    } else {                                 // bias vectors
        const int t = p - 266;
        const float *bsel, *W, *badd;
        float* out;
        int N, bx;
        if (t < 27) {
            int z = t / 9; bx = t % 9; N = EE;
            bsel = (z == 0) ? bq  : (z == 1) ? bk  : bv;
            W    = (z == 0) ? Wiq : (z == 1) ? Wik : Wiv;
            badd = (z == 0) ? biq : (z == 1) ? bik : biv;
            out  = (z == 0) ? bqc : (z == 1) ? bkc : bvc;
        } else {
            bx = t - 27; N = DD;
            bsel = bo; W = W_O; badd = nullptr; out = bvec;
        }
        float* bs = sm;                      // 576
        float* red = sm + 576;               // 256
        for (int i = tid; i < 144; i += 256)
            *((float4*)&bs[i * 4]) = *(const float4*)(bsel + i * 4);
        __syncthreads();
        const int wave = tid >> 6, lane = tid & 63;
        const int colg = bx * 64 + lane;
        const int colc = (colg < N) ? colg : (N - 1);
        float acc = 0.f;
        for (int k = wave * 144; k < wave * 144 + 144; ++k)
            acc += bs[k] * W[(size_t)k * N + colc];
        red[wave * 64 + lane] = acc;
        __syncthreads();
        if (tid < 64 && bx * 64 + tid < N) {
            float s = red[tid] + red[64 + tid] + red[128 + tid] + red[192 + tid];
            out[bx * 64 + tid] = s + (badd ? badd[bx * 64 + tid] : 0.f);
        }
    }
}

// ---------------------------------------------------------------------------
// k_qkv: {q,k,v} = C @ Wzc + bzc  (M=256, K=144, N=576), XCD-swizzled.
// 8-row tiles; wave Kc=36, single 36-load group; LDS reduce. grid 1024.
// (verbatim proven round-0 kernel)
// ---------------------------------------------------------------------------
__global__ __launch_bounds__(256) void k_qkv(
    const float* __restrict__ C,
    const float* __restrict__ Wqc, const float* __restrict__ Wkc, const float* __restrict__ Wvc,
    const float* __restrict__ bqc, const float* __restrict__ bkc, const float* __restrict__ bvc,
    float* __restrict__ q, float* __restrict__ kb, float* __restrict__ v)
{
    const int p = blockIdx.x;
    const int xcd = p & 7, qq = p >> 3;
    const int mb = qq & 31, gslot = qq >> 5;
    const int g = xcd + 8 * gslot;           // block-uniform
    if (g >= 27) return;
    const int bx = g % 9, z = g / 9;
    const float* W  = (z == 0) ? Wqc : (z == 1) ? Wkc : Wvc;
    const float* bi = (z == 0) ? bqc : (z == 1) ? bkc : bvc;
    float*      out = (z == 0) ? q   : (z == 1) ? kb  : v;
    const int tid = threadIdx.x;

    __shared__ union { float As[8 * 148]; float red[2048]; } u;
    for (int idx = tid; idx < 8 * 36; idx += 256) {
        int r = idx / 36, c = idx % 36;
        *((float4*)&u.As[r * 148 + c * 4]) =
            *(const float4*)(C + (size_t)(mb * 8 + r) * DD + c * 4);
    }
    __syncthreads();
    const int wave = tid >> 6, lane = tid & 63;
    const int colg = bx * 64 + lane;
    const float* Wp = W + (size_t)(wave * 36) * EE + colg;
    float acc[8] = {};
    float wv[36];
    #pragma unroll
    for (int j = 0; j < 36; ++j) wv[j] = Wp[(size_t)j * EE];
    const int kbase = wave * 36;
    #pragma unroll
    for (int j4 = 0; j4 < 9; ++j4) {
        #pragma unroll
        for (int r = 0; r < 8; ++r) {
            float4 a4 = *(const float4*)&u.As[r * 148 + kbase + j4 * 4];
            acc[r] += a4.x * wv[j4 * 4 + 0] + a4.y * wv[j4 * 4 + 1]
                    + a4.z * wv[j4 * 4 + 2] + a4.w * wv[j4 * 4 + 3];
        }
    }
    __syncthreads();
    #pragma unroll
    for (int r = 0; r < 8; ++r) u.red[wave * 512 + r * 64 + lane] = acc[r];
    __syncthreads();
    #pragma unroll
    for (int qi = 0; qi < 2; ++qi) {
        int idx = tid + qi * 256;
        int r = idx >> 6, cl = idx & 63;
        int col = bx * 64 + cl;
        float s = u.red[idx] + u.red[512 + idx]
                + u.red[1024 + idx] + u.red[1536 + idx];
        out[(size_t)(mb * 8 + r) * EE + col] = s + bi[col];
    }
}

// ---------------------------------------------------------------------------
// Fused scores + attention reduction (verbatim proven round-0 kernel).
// ---------------------------------------------------------------------------
__global__ __launch_bounds__(256) void k_attn(
    const int* __restrict__ state, const float* __restrict__ q,
    const float* __restrict__ kmat, const float* __restrict__ v,
    float* __restrict__ ctxsum, float* __restrict__ cnt)
{
    __shared__ int lst[NAG];
    __shared__ int cnt_s;
    __shared__ float w4[NH][NAG];
    __shared__ float qh[CMAX][HDIM + 1];
    __shared__ float kh[CMAX][HDIM + 1];
    __shared__ float Sl[CMAX][CMAX + 1];
    const int i = blockIdx.x, tid = threadIdx.x;
    if (tid == 0) cnt_s = 0;
    __syncthreads();
    {
        int xi = state[2 * i], yi = state[2 * i + 1];
        int xj = state[2 * tid], yj = state[2 * tid + 1];
        int dx = xi - xj; if (dx < 0) dx = -dx;
        int dy = yi - yj; if (dy < 0) dy = -dy;
        if (tid > i && dx <= 4 && dy <= 2) {
            int p = atomicAdd(&cnt_s, 1);
            lst[p] = tid;
        }
    }
    __syncthreads();
    const int c = cnt_s;                 // block-uniform
    if (tid == 0) cnt[i] = (float)c;
    if (c == 0) {
        for (int e = tid; e < EE; e += 256) ctxsum[i * EE + e] = 0.f;
        return;
    }
    if (c <= CMAX) {
        for (int h = 0; h < NH; ++h) {
            for (int idx = tid; idx < c * HDIM; idx += 256) {
                int jj = idx / HDIM, d = idx % HDIM;
                qh[jj][d] = q[lst[jj] * EE + h * HDIM + d];
                kh[jj][d] = kmat[lst[jj] * EE + h * HDIM + d];
            }
            __syncthreads();
            for (int pp = tid; pp < c * c; pp += 256) {
                int jj = pp / c, kk = pp % c;
                float acc = 0.f;
                for (int d = 0; d < HDIM; ++d) acc += qh[jj][d] * kh[kk][d];
                Sl[jj][kk] = acc * (1.0f / 12.0f);
            }
            __syncthreads();
            if (tid < c) {
                float m = -1e30f;
                for (int kk = 0; kk < c; ++kk) m = fmaxf(m, Sl[tid][kk]);
                float zz = 0.f;
                for (int kk = 0; kk < c; ++kk) zz += __expf(Sl[tid][kk] - m);
                float inv = 1.f / fmaxf(zz, 1e-9f);
                for (int kk = 0; kk < c; ++kk)
                    Sl[tid][kk] = __expf(Sl[tid][kk] - m) * inv;
            }
            __syncthreads();
            if (tid < c) {
                float s = 0.f;
                for (int jj = 0; jj < c; ++jj) s += Sl[jj][tid];
                w4[h][tid] = s;
            }
            __syncthreads();
        }
    } else {
        for (int idx = tid; idx < NH * c; idx += 256) w4[idx / c][idx % c] = 0.f;
        __syncthreads();
        for (int pnh = tid; pnh < NH * c; pnh += 256) {
            int h = pnh / c, jj = pnh % c;
            const float* qrow = q + lst[jj] * EE + h * HDIM;
            float m = -1e30f;
            for (int kk = 0; kk < c; ++kk) {
                const float* krow = kmat + lst[kk] * EE + h * HDIM;
                float a = 0.f;
                for (int d = 0; d < HDIM; ++d) a += qrow[d] * krow[d];
                m = fmaxf(m, a * (1.0f / 12.0f));
            }
            float zz = 0.f;
            for (int kk = 0; kk < c; ++kk) {
                const float* krow = kmat + lst[kk] * EE + h * HDIM;
                float a = 0.f;
                for (int d = 0; d < HDIM; ++d) a += qrow[d] * krow[d];
                zz += __expf(a * (1.0f / 12.0f) - m);
            }
            float inv = 1.f / fmaxf(zz, 1e-9f);
            for (int kk = 0; kk < c; ++kk) {
                const float* krow = kmat + lst[kk] * EE + h * HDIM;
                float a = 0.f;
                for (int d = 0; d < HDIM; ++d) a += qrow[d] * krow[d];
                atomicAdd(&w4[h][kk], __expf(a * (1.0f / 12.0f) - m) * inv);
            }
        }
        __syncthreads();
    }
    for (int e = tid; e < EE; e += 256) {
        int h = e / HDIM;
        float a0 = 0.f, a1 = 0.f;
        int t = 0;
        for (; t + 1 < c; t += 2) {
            a0 += w4[h][t] * v[lst[t] * EE + e];
            a1 += w4[h][t + 1] * v[lst[t + 1] * EE + e];
        }
        if (t < c) a0 += w4[h][t] * v[lst[t] * EE + e];
        ctxsum[i * EE + e] = a0 + a1;
    }
}

// ---------------------------------------------------------------------------
// k_tail: h[8 x 144] = ctx[8 rows x 576] @ Wc + cnt*bvec; then dueling head.
// 32 blocks x 8 agents (halves Wc re-read traffic vs 4-agent version);
// 144 threads compute cols (G=32 reg double-buffer); head: 2 agents per wave.
// ---------------------------------------------------------------------------
__global__ __launch_bounds__(256) void k_tail(
    const float* __restrict__ ctx, const float* __restrict__ Wc,
    const float* __restrict__ cnt, const float* __restrict__ bvec,
    const float* __restrict__ W_val, const float* __restrict__ b_val,
    const float* __restrict__ W_adv, const float* __restrict__ b_adv,
    float* __restrict__ out)
{
    __shared__ float As[8][EE];
    __shared__ float hb[8][DD];
    const int b = blockIdx.x, tid = threadIdx.x;
    const int a0 = b * 8;
    for (int idx = tid; idx < 8 * (EE / 4); idx += 256) {
        int r = idx / (EE / 4), c4 = idx % (EE / 4);
        *((float4*)&As[r][c4 * 4]) =
            *(const float4*)(ctx + (size_t)(a0 + r) * EE + c4 * 4);
    }
    __syncthreads();
    if (tid < DD) {
        const int col = tid;
        const float* Wp = Wc + col;
        float ac[8] = {};
        float wv[32], wn[32];
        #pragma unroll
        for (int j = 0; j < 32; ++j) wv[j] = Wp[(size_t)j * DD];
        for (int gI = 0; gI < 18; ++gI) {
            if (gI + 1 < 18) {
                const float* Wn = Wp + (size_t)(gI + 1) * 32 * DD;
                #pragma unroll
                for (int j = 0; j < 32; ++j) wn[j] = Wn[(size_t)j * DD];
            }
            const int kbase = gI * 32;
            #pragma unroll
            for (int j = 0; j < 32; ++j) {
                float w = wv[j];
                #pragma unroll
                for (int s = 0; s < 8; ++s) ac[s] += As[s][kbase + j] * w;
            }
            #pragma unroll
            for (int j = 0; j < 32; ++j) wv[j] = wn[j];
        }
        float bvc = bvec[col];
        #pragma unroll
        for (int s = 0; s < 8; ++s) hb[s][col] = ac[s] + cnt[a0 + s] * bvc;
    }
    __syncthreads();
    const int wave = tid >> 6, lane = tid & 63;
    for (int s = 0; s < 2; ++s) {
        const int ag = wave * 2 + s;         // agent index within block
        float h0 = hb[ag][lane], h1 = hb[ag][lane + 64];
        float h2 = (lane < 16) ? hb[ag][lane + 128] : 0.f;
        float red[6];
        for (int o = 0; o < 6; ++o) {
            float p;
            if (o < 5) {
                p = h0 * W_adv[lane * ACT + o] + h1 * W_adv[(lane + 64) * ACT + o];
                if (lane < 16) p += h2 * W_adv[(lane + 128) * ACT + o];
            } else {
                p = h0 * W_val[lane] + h1 * W_val[lane + 64];
                if (lane < 16) p += h2 * W_val[lane + 128];
            }
            for (int off = 32; off; off >>= 1) p += __shfl_xor(p, off);
            red[o] = p;
        }
        if (lane == 0) {
            float a[ACT], mean = 0.f;
            for (int o = 0; o < ACT; ++o) { a[o] = red[o] + b_adv[o]; mean += a[o]; }
            mean *= (1.0f / ACT);
            float V = red[5] + b_val[0];
            for (int o = 0; o < ACT; ++o) out[(a0 + ag) * ACT + o] = V + a[o] - mean;
        }
    }
}

// ---------------------------------------------------------------------------
extern "C" void kernel_launch(void* const* d_in, const int* in_sizes, int n_in,
                              void* d_out, int out_size, void* d_ws, size_t ws_size,
                              hipStream_t stream)
{
    const float* hidden = (const float*)d_in[0];
    const float* action = (const float*)d_in[1];
    const int*   state  = (const int*)d_in[2];

    float* ws = (float*)d_ws;
    float* C    = ws;                        // 256*144 = 36864
    float* Wqc  = C    + NAG * DD;           // 144*576 = 82944 each
    float* Wkc  = Wqc  + DD * EE;
    float* Wvc  = Wkc  + DD * EE;
    float* Wc   = Wvc  + DD * EE;            // 576*144 = 82944
    float* bqc  = Wc   + EE * DD;            // 576 each
    float* bkc  = bqc  + EE;
    float* bvc  = bkc  + EE;
    float* bvec = bvc  + EE;                 // 144
    float* q    = bvec + DD;                 // 256*576 each
    float* kb   = q    + NAG * EE;
    float* v    = kb   + NAG * EE;
    float* ctx  = v    + NAG * EE;
    float* cnt  = ctx  + NAG * EE;           // 256
    // total ws ~3.9 MB

    // k_pre: weight products (R=24 tiles) + biases + enc C  (296 blocks)
    k_pre<<<296, 256, 0, stream>>>(hidden, action,
        (const float*)d_in[3], (const float*)d_in[4],
        (const float*)d_in[5], (const float*)d_in[7], (const float*)d_in[9],
        (const float*)d_in[6], (const float*)d_in[8], (const float*)d_in[10],
        (const float*)d_in[11], (const float*)d_in[13], (const float*)d_in[15],
        (const float*)d_in[12], (const float*)d_in[14], (const float*)d_in[16],
        (const float*)d_in[17], (const float*)d_in[18], (const float*)d_in[19],
        C, Wqc, Wkc, Wvc, Wc, bqc, bkc, bvc, bvec);

    // k_qkv: q/k/v = C @ Wzc + bzc  (K=144, swizzled, 864 active)
    k_qkv<<<1024, 256, 0, stream>>>(C, Wqc, Wkc, Wvc, bqc, bkc, bvc, q, kb, v);

    // fused scores+attention
    k_attn<<<NAG, 256, 0, stream>>>(state, q, kb, v, ctx, cnt);

    // k_tail: h = ctx @ Wc + cnt*bvec; dueling head (8 agents/block)
    k_tail<<<32, 256, 0, stream>>>(ctx, Wc, cnt, bvec,
        (const float*)d_in[20], (const float*)d_in[21],
        (const float*)d_in[22], (const float*)d_in[23], (float*)d_out);
}